// Round 2
// baseline (5763.850 us; speedup 1.0000x reference)
//
#include <hip/hip_runtime.h>

// Graph-transformer layer, MI355X. N nodes, E edges, H=128, 4 heads x d=32.
// Restructurings: (1) he@W = h_E@W_top + (y@W_bot)[col] (gather commutes with
// matmul) -> edge GEMMs are [E,128]@[128,128] only; (2) softmax without the
// segment-max pass (logits can't overflow fp32 exp); (3) bf16 MFMA 16x16x32.
// R1 fixes: edge_index treated as int32 (runtime-probed int64 fallback),
// H1 lives in d_out (ws ~78MB), own zero-kernel instead of hipMemsetAsync.

typedef __bf16 bf16x8 __attribute__((ext_vector_type(8)));
typedef float f32x4 __attribute__((ext_vector_type(4)));
typedef unsigned short u16x8 __attribute__((ext_vector_type(8)));

#define DEV static __device__ __forceinline__

DEV unsigned short f2b(float f){
  union { float f; unsigned u; } v; v.f = f;
  unsigned r = (v.u + 0x7FFFu + ((v.u >> 16) & 1u)) >> 16;   // RNE
  return (unsigned short)r;
}
DEV float b2f(unsigned short h){
  union { unsigned u; float f; } v; v.u = ((unsigned)h) << 16; return v.f;
}
DEV f32x4 mfma16(bf16x8 a, bf16x8 b, f32x4 c){
  return __builtin_amdgcn_mfma_f32_16x16x32_bf16(a, b, c, 0, 0, 0);
}
DEV u16x8 pack8(float4 a, float4 b){
  u16x8 p;
  p[0]=f2b(a.x); p[1]=f2b(a.y); p[2]=f2b(a.z); p[3]=f2b(a.w);
  p[4]=f2b(b.x); p[5]=f2b(b.y); p[6]=f2b(b.z); p[7]=f2b(b.w);
  return p;
}
DEV float sspf(float x){  // shifted softplus
  return fmaxf(x, 0.f) + log1pf(expf(-fabsf(x))) - 0.69314718055994531f;
}
// edge_index layout probe: harness normally passes int32; if the raw int64
// words were kept, every odd int32 (high word, values < 2^31) is zero.
DEV int idx64probe(const int* __restrict__ ei){
  return (ei[1] | ei[3] | ei[5] | ei[7] | ei[9]) == 0;
}
DEV int ld_row(const int* __restrict__ ei, long eg, long E, int is64, int N){
  int v = is64 ? ei[2*eg] : ei[eg];
  return min(max(v, 0), N - 1);
}
DEV int ld_col(const int* __restrict__ ei, long eg, long E, int is64, int N){
  int v = is64 ? ei[2*(E + eg)] : ei[E + eg];
  return min(max(v, 0), N - 1);
}

// 128x128 (M x N) += A(128x128 bf16, LDS, XOR-swizzled) @ WT(bf16, global,
// stored [n][k]). 4 waves, each does a 64x64 tile via 4x4 16x16x32 MFMAs.
DEV void mma128(const unsigned short* At, const unsigned short* __restrict__ WT,
                int t, f32x4 (&acc)[4][4]){
  const int l = t & 63;
  const int wm = (t >> 7) & 1, wn = (t >> 6) & 1;
#pragma unroll
  for (int m = 0; m < 4; ++m)
#pragma unroll
    for (int n = 0; n < 4; ++n)
      acc[m][n] = f32x4{0.f, 0.f, 0.f, 0.f};
#pragma unroll
  for (int kk = 0; kk < 4; ++kk){
    bf16x8 a[4], b[4];
#pragma unroll
    for (int m = 0; m < 4; ++m){
      int row = wm*64 + m*16 + (l & 15);
      unsigned byt = ((unsigned)(row*256 + kk*64 + ((l >> 4) & 3)*16))
                   ^ (((unsigned)(row & 7)) << 4);
      a[m] = *(const bf16x8*)((const char*)At + byt);
    }
#pragma unroll
    for (int n = 0; n < 4; ++n){
      int col = wn*64 + n*16 + (l & 15);
      b[n] = *(const bf16x8*)(WT + col*128 + kk*32 + ((l >> 4) & 3)*8);
    }
#pragma unroll
    for (int m = 0; m < 4; ++m)
#pragma unroll
      for (int n = 0; n < 4; ++n)
        acc[m][n] = mfma16(a[m], b[n], acc[m][n]);
  }
}

__global__ void k_zero(float4* __restrict__ p, long n){
  long i = (long)blockIdx.x * blockDim.x + threadIdx.x;
  const long st = (long)gridDim.x * blockDim.x;
  const float4 z = {0.f, 0.f, 0.f, 0.f};
  for (; i < n; i += st) p[i] = z;
}

// ---- weight prep: fp32 [k][n] -> bf16 [n][k] blobs (once per launch) ----
__global__ void k_wprep(const float* __restrict__ WQ, const float* __restrict__ WK,
                        const float* __restrict__ WV, const float* __restrict__ WO,
                        const float* __restrict__ Wi, const float* __restrict__ Wo2,
                        unsigned short* WQT, unsigned short* WKtT, unsigned short* WKbT,
                        unsigned short* WVtT, unsigned short* WVbT, unsigned short* WOT,
                        unsigned short* WinT, unsigned short* WouT){
  int id = blockIdx.x * 256 + threadIdx.x;
  int n = id >> 7, k = id & 127;
  int d = n * 128 + k;
  WQT[d]  = f2b(WQ[k*128 + n]);
  WKtT[d] = f2b(WK[k*128 + n]);
  WKbT[d] = f2b(WK[(k+128)*128 + n]);
  WVtT[d] = f2b(WV[k*128 + n]);
  WVbT[d] = f2b(WV[(k+128)*128 + n]);
  WOT[d]  = f2b(WO[k*128 + n]);
  WinT[d] = f2b(Wi[k*128 + n]);
  WouT[d] = f2b(Wo2[k*128 + n]);
}

// ---- node prep: LN1(h_V) -> y ; Q=y@WQ, YK=y@WKbot, YV=y@WVbot (bf16) ----
__global__ __launch_bounds__(256) void k_nodeprep(
    const float* __restrict__ hV, const float* __restrict__ l1s, const float* __restrict__ l1b,
    const unsigned short* __restrict__ WQT, const unsigned short* __restrict__ WKbT,
    const unsigned short* __restrict__ WVbT,
    unsigned short* __restrict__ Qbf, unsigned short* __restrict__ YKbf,
    unsigned short* __restrict__ YVbf, int N){
  __shared__ unsigned short At[128*128];
  __shared__ float ps[256], pss[256];
  __shared__ float scs[128], bis[128];
  const int t = threadIdx.x;
  if (t < 128){ scs[t] = l1s[t]; bis[t] = l1b[t]; }
  const int r0 = blockIdx.x * 128;
  const int rl = t & 127, hf = t >> 7;
  const int r = r0 + rl;
  const float4* xp = (const float4*)(hV + (size_t)r*128 + hf*64);
  float s = 0.f, ss = 0.f;
  if (r < N){
#pragma unroll
    for (int i = 0; i < 16; ++i){
      float4 v = xp[i];
      s  += (v.x + v.y) + (v.z + v.w);
      ss += (v.x*v.x + v.y*v.y) + (v.z*v.z + v.w*v.w);
    }
  }
  ps[t] = s; pss[t] = ss;
  __syncthreads();
  const float mu  = (ps[t] + ps[t ^ 128]) * 0.0078125f;
  const float var = (pss[t] + pss[t ^ 128]) * 0.0078125f - mu*mu;
  const float rs  = rsqrtf(var + 1e-5f);
#pragma unroll
  for (int i = 0; i < 8; ++i){
    const int c = hf*64 + i*8;
    u16x8 p = {0,0,0,0,0,0,0,0};
    if (r < N){
      float4 v0 = xp[2*i], v1 = xp[2*i+1];
      p[0] = f2b((v0.x - mu)*rs*scs[c+0] + bis[c+0]);
      p[1] = f2b((v0.y - mu)*rs*scs[c+1] + bis[c+1]);
      p[2] = f2b((v0.z - mu)*rs*scs[c+2] + bis[c+2]);
      p[3] = f2b((v0.w - mu)*rs*scs[c+3] + bis[c+3]);
      p[4] = f2b((v1.x - mu)*rs*scs[c+4] + bis[c+4]);
      p[5] = f2b((v1.y - mu)*rs*scs[c+5] + bis[c+5]);
      p[6] = f2b((v1.z - mu)*rs*scs[c+6] + bis[c+6]);
      p[7] = f2b((v1.w - mu)*rs*scs[c+7] + bis[c+7]);
    }
    *(u16x8*)((char*)At + (((unsigned)(rl*256 + c*2)) ^ (((unsigned)(rl & 7)) << 4))) = p;
  }
  __syncthreads();
  const int l = t & 63, wm = (t >> 7) & 1, wn = (t >> 6) & 1;
  f32x4 acc[4][4];
  for (int g = 0; g < 3; ++g){
    const unsigned short* WT = (g == 0) ? WQT : (g == 1) ? WKbT : WVbT;
    unsigned short* O = (g == 0) ? Qbf : (g == 1) ? YKbf : YVbf;
    mma128(At, WT, t, acc);
#pragma unroll
    for (int m = 0; m < 4; ++m)
#pragma unroll
      for (int reg = 0; reg < 4; ++reg){
        int row = wm*64 + m*16 + ((l >> 4) & 3)*4 + reg;
        int gr = r0 + row;
        if (gr < N){
#pragma unroll
          for (int n = 0; n < 4; ++n){
            int col = wn*64 + n*16 + (l & 15);
            O[(size_t)gr*128 + col] = f2b(acc[m][n][reg]);
          }
        }
      }
  }
}

// ---- edge pass 1: K = h_E@WKtop + YK[col]; logits; exp; atomic denom ----
__global__ __launch_bounds__(256, 2) void k_edge1(
    const float* __restrict__ hE, const int* __restrict__ ei,
    const unsigned short* __restrict__ WKtT, const unsigned short* __restrict__ Qbf,
    const unsigned short* __restrict__ YKbf,
    float* __restrict__ exw, float* __restrict__ den, long E, int N){
  __shared__ unsigned short At[128*128];
  __shared__ unsigned short Kt[128*128];
  const int t = threadIdx.x;
  const long e0 = (long)blockIdx.x * 128;
  const int is64 = idx64probe(ei);
#pragma unroll
  for (int i = 0; i < 8; ++i){           // stage h_E tile -> bf16, swizzled
    int cc = t + i*256;
    int row = cc >> 4, ck = (cc & 15)*8;
    u16x8 p = {0,0,0,0,0,0,0,0};
    if (e0 + row < E){
      const float4* src = (const float4*)(hE + (e0 + row)*128 + ck);
      p = pack8(src[0], src[1]);
    }
    *(u16x8*)((char*)At + (((unsigned)(row*256 + ck*2)) ^ (((unsigned)(row & 7)) << 4))) = p;
  }
  {                                       // prefill K tile with YK[col[e]]
    const int e = t >> 1, hf = t & 1;
    const long eg = e0 + e;
    const int c = (eg < E) ? ld_col(ei, eg, E, is64, N) : 0;
    const u16x8* src = (const u16x8*)(YKbf + (size_t)c*128 + hf*64);
#pragma unroll
    for (int i = 0; i < 8; ++i)
      *(u16x8*)((char*)Kt + (((unsigned)(e*256 + hf*128 + i*16)) ^ (((unsigned)(e & 7)) << 4))) = src[i];
  }
  __syncthreads();
  f32x4 acc[4][4];
  mma128(At, WKtT, t, acc);
  {                                       // K += EK (RMW in LDS, bf16)
    const int l = t & 63, wm = (t >> 7) & 1, wn = (t >> 6) & 1;
#pragma unroll
    for (int m = 0; m < 4; ++m)
#pragma unroll
      for (int reg = 0; reg < 4; ++reg){
        int er = wm*64 + m*16 + ((l >> 4) & 3)*4 + reg;
#pragma unroll
        for (int n = 0; n < 4; ++n){
          int col = wn*64 + n*16 + (l & 15);
          unsigned short* p = (unsigned short*)((char*)Kt +
              (((unsigned)(er*256 + col*2)) ^ (((unsigned)(er & 7)) << 4)));
          *p = f2b(acc[m][n][reg] + b2f(*p));
        }
      }
  }
  __syncthreads();
  {                                       // logits = Q[row].K per head; exp
    const int e = t >> 1, hf = t & 1;
    const long eg = e0 + e;
    const int r = (eg < E) ? ld_row(ei, eg, E, is64, N) : 0;
    const u16x8* qp = (const u16x8*)(Qbf + (size_t)r*128 + hf*64);
    float lg0 = 0.f, lg1 = 0.f;
#pragma unroll
    for (int i = 0; i < 8; ++i){
      u16x8 q = qp[i];
      u16x8 k = *(const u16x8*)((const char*)Kt +
          (((unsigned)(e*256 + hf*128 + i*16)) ^ (((unsigned)(e & 7)) << 4)));
      float d = 0.f;
#pragma unroll
      for (int j = 0; j < 8; ++j) d += b2f(q[j]) * b2f(k[j]);
      if (i < 4) lg0 += d; else lg1 += d;
    }
    if (eg < E){
      float x0 = expf(lg0), x1 = expf(lg1);
      exw[eg*4 + 2*hf]     = x0;
      exw[eg*4 + 2*hf + 1] = x1;
      atomicAdd(&den[(size_t)r*4 + 2*hf],     x0);
      atomicAdd(&den[(size_t)r*4 + 2*hf + 1], x1);
    }
  }
}

// ---- edge pass 2: V = h_E@WVtop + YV[col]; msg = alpha*V; scatter-add ----
__global__ __launch_bounds__(256, 2) void k_edge2(
    const float* __restrict__ hE, const int* __restrict__ ei,
    const unsigned short* __restrict__ WVtT, const unsigned short* __restrict__ YVbf,
    const float* __restrict__ exw, const float* __restrict__ den,
    float* __restrict__ agg, long E, int N){
  __shared__ unsigned short At[128*128];
  __shared__ unsigned short Vt[128*128];
  const int t = threadIdx.x;
  const long e0 = (long)blockIdx.x * 128;
  const int is64 = idx64probe(ei);
#pragma unroll
  for (int i = 0; i < 8; ++i){
    int cc = t + i*256;
    int row = cc >> 4, ck = (cc & 15)*8;
    u16x8 p = {0,0,0,0,0,0,0,0};
    if (e0 + row < E){
      const float4* src = (const float4*)(hE + (e0 + row)*128 + ck);
      p = pack8(src[0], src[1]);
    }
    *(u16x8*)((char*)At + (((unsigned)(row*256 + ck*2)) ^ (((unsigned)(row & 7)) << 4))) = p;
  }
  {
    const int e = t >> 1, hf = t & 1;
    const long eg = e0 + e;
    const int c = (eg < E) ? ld_col(ei, eg, E, is64, N) : 0;
    const u16x8* src = (const u16x8*)(YVbf + (size_t)c*128 + hf*64);
#pragma unroll
    for (int i = 0; i < 8; ++i)
      *(u16x8*)((char*)Vt + (((unsigned)(e*256 + hf*128 + i*16)) ^ (((unsigned)(e & 7)) << 4))) = src[i];
  }
  __syncthreads();
  f32x4 acc[4][4];
  mma128(At, WVtT, t, acc);
  {
    const int l = t & 63, wm = (t >> 7) & 1, wn = (t >> 6) & 1;
#pragma unroll
    for (int m = 0; m < 4; ++m)
#pragma unroll
      for (int reg = 0; reg < 4; ++reg){
        int er = wm*64 + m*16 + ((l >> 4) & 3)*4 + reg;
#pragma unroll
        for (int n = 0; n < 4; ++n){
          int col = wn*64 + n*16 + (l & 15);
          unsigned short* p = (unsigned short*)((char*)Vt +
              (((unsigned)(er*256 + col*2)) ^ (((unsigned)(er & 7)) << 4)));
          *p = f2b(acc[m][n][reg] + b2f(*p));
        }
      }
  }
  __syncthreads();
  {
    const int e = t >> 1, hf = t & 1;
    const long eg = e0 + e;
    if (eg < E){
      const int r = ld_row(ei, eg, E, is64, N);
      const float inv = 0.17677669529663687f;  // 1/sqrt(32), applied after softmax
      float a0 = exw[eg*4 + 2*hf]     / den[(size_t)r*4 + 2*hf]     * inv;
      float a1 = exw[eg*4 + 2*hf + 1] / den[(size_t)r*4 + 2*hf + 1] * inv;
      float* dst = agg + (size_t)r*128 + hf*64;
#pragma unroll
      for (int i = 0; i < 8; ++i){
        u16x8 v = *(const u16x8*)((const char*)Vt +
            (((unsigned)(e*256 + hf*128 + i*16)) ^ (((unsigned)(e & 7)) << 4)));
        float al = (i < 4) ? a0 : a1;
#pragma unroll
        for (int j = 0; j < 8; ++j)
          atomicAdd(dst + i*8 + j, al * b2f(v[j]));
      }
    }
  }
}

// ---- attn out: h1 = h_V + ssp(aggr)@W_O ----
__global__ __launch_bounds__(256) void k_attnout(
    const float* __restrict__ hV, const float* __restrict__ agg,
    const unsigned short* __restrict__ WOT, float* __restrict__ H1, int N){
  __shared__ unsigned short At[128*128];
  const int t = threadIdx.x;
  const int r0 = blockIdx.x * 128;
  const int rl = t & 127, hf = t >> 7;
  const int r = r0 + rl;
  const float4* ap = (const float4*)(agg + (size_t)r*128 + hf*64);
#pragma unroll
  for (int i = 0; i < 8; ++i){
    u16x8 p = {0,0,0,0,0,0,0,0};
    if (r < N){
      float4 v0 = ap[2*i], v1 = ap[2*i+1];
      p[0]=f2b(sspf(v0.x)); p[1]=f2b(sspf(v0.y)); p[2]=f2b(sspf(v0.z)); p[3]=f2b(sspf(v0.w));
      p[4]=f2b(sspf(v1.x)); p[5]=f2b(sspf(v1.y)); p[6]=f2b(sspf(v1.z)); p[7]=f2b(sspf(v1.w));
    }
    *(u16x8*)((char*)At + (((unsigned)(rl*256 + hf*128 + i*16)) ^ (((unsigned)(rl & 7)) << 4))) = p;
  }
  __syncthreads();
  f32x4 acc[4][4];
  mma128(At, WOT, t, acc);
  const int l = t & 63, wm = (t >> 7) & 1, wn = (t >> 6) & 1;
#pragma unroll
  for (int m = 0; m < 4; ++m)
#pragma unroll
    for (int reg = 0; reg < 4; ++reg){
      int row = wm*64 + m*16 + ((l >> 4) & 3)*4 + reg;
      int gr = r0 + row;
      if (gr < N){
#pragma unroll
        for (int n = 0; n < 4; ++n){
          int col = wn*64 + n*16 + (l & 15);
          H1[(size_t)gr*128 + col] = acc[m][n][reg] + hV[(size_t)gr*128 + col];
        }
      }
    }
}

// ---- FFN: out = h1 + (relu(LN2(h1)@Win + bin)@Wout + bout), out==H1 ok ----
__global__ __launch_bounds__(256) void k_ffn(
    const float* __restrict__ H1, const float* __restrict__ l2s, const float* __restrict__ l2b,
    const unsigned short* __restrict__ WinT, const unsigned short* __restrict__ WouT,
    const float* __restrict__ bin, const float* __restrict__ bou,
    float* __restrict__ out, int N){
  __shared__ unsigned short At[128*128];
  __shared__ float ps[256], pss[256];
  __shared__ float scs[128], bis[128];
  const int t = threadIdx.x;
  if (t < 128){ scs[t] = l2s[t]; bis[t] = l2b[t]; }
  const int r0 = blockIdx.x * 128;
  const int rl = t & 127, hf = t >> 7;
  const int r = r0 + rl;
  const float4* xp = (const float4*)(H1 + (size_t)r*128 + hf*64);
  float s = 0.f, ss = 0.f;
  float4 xv[16];
  if (r < N){
#pragma unroll
    for (int i = 0; i < 16; ++i){
      float4 v = xp[i];
      xv[i] = v;
      s  += (v.x + v.y) + (v.z + v.w);
      ss += (v.x*v.x + v.y*v.y) + (v.z*v.z + v.w*v.w);
    }
  }
  ps[t] = s; pss[t] = ss;
  __syncthreads();
  const float mu  = (ps[t] + ps[t ^ 128]) * 0.0078125f;
  const float var = (pss[t] + pss[t ^ 128]) * 0.0078125f - mu*mu;
  const float rs  = rsqrtf(var + 1e-5f);
#pragma unroll
  for (int i = 0; i < 8; ++i){
    const int c = hf*64 + i*8;
    u16x8 p = {0,0,0,0,0,0,0,0};
    if (r < N){
      float4 v0 = xv[2*i], v1 = xv[2*i+1];
      p[0] = f2b((v0.x - mu)*rs*scs[c+0] + bis[c+0]);
      p[1] = f2b((v0.y - mu)*rs*scs[c+1] + bis[c+1]);
      p[2] = f2b((v0.z - mu)*rs*scs[c+2] + bis[c+2]);
      p[3] = f2b((v0.w - mu)*rs*scs[c+3] + bis[c+3]);
      p[4] = f2b((v1.x - mu)*rs*scs[c+4] + bis[c+4]);
      p[5] = f2b((v1.y - mu)*rs*scs[c+5] + bis[c+5]);
      p[6] = f2b((v1.z - mu)*rs*scs[c+6] + bis[c+6]);
      p[7] = f2b((v1.w - mu)*rs*scs[c+7] + bis[c+7]);
    }
    *(u16x8*)((char*)At + (((unsigned)(rl*256 + c*2)) ^ (((unsigned)(rl & 7)) << 4))) = p;
  }
  __syncthreads();
  f32x4 acc[4][4];
  mma128(At, WinT, t, acc);
  const int l = t & 63, wm = (t >> 7) & 1, wn = (t >> 6) & 1;
  unsigned short hv[4][4][4];
#pragma unroll
  for (int m = 0; m < 4; ++m)
#pragma unroll
    for (int n = 0; n < 4; ++n)
#pragma unroll
      for (int reg = 0; reg < 4; ++reg){
        int col = wn*64 + n*16 + (l & 15);
        float v = acc[m][n][reg] + bin[col];
        hv[m][n][reg] = f2b(fmaxf(v, 0.f));
      }
  __syncthreads();
#pragma unroll
  for (int m = 0; m < 4; ++m)
#pragma unroll
    for (int reg = 0; reg < 4; ++reg){
      int row = wm*64 + m*16 + ((l >> 4) & 3)*4 + reg;
#pragma unroll
      for (int n = 0; n < 4; ++n){
        int col = wn*64 + n*16 + (l & 15);
        *(unsigned short*)((char*)At +
            (((unsigned)(row*256 + col*2)) ^ (((unsigned)(row & 7)) << 4))) = hv[m][n][reg];
      }
    }
  __syncthreads();
  mma128(At, WouT, t, acc);
#pragma unroll
  for (int m = 0; m < 4; ++m)
#pragma unroll
    for (int reg = 0; reg < 4; ++reg){
      int row = wm*64 + m*16 + ((l >> 4) & 3)*4 + reg;
      int gr = r0 + row;
      if (gr < N){
#pragma unroll
        for (int n = 0; n < 4; ++n){
          int col = wn*64 + n*16 + (l & 15);
          out[(size_t)gr*128 + col] = acc[m][n][reg] + bou[col] + H1[(size_t)gr*128 + col];
        }
      }
    }
}

extern "C" void kernel_launch(void* const* d_in, const int* in_sizes, int n_in,
                              void* d_out, int out_size, void* d_ws, size_t ws_size,
                              hipStream_t stream)
{
  const float* hV  = (const float*)d_in[0];
  const float* hE  = (const float*)d_in[1];
  const int*   ei  = (const int*)d_in[2];
  const float* WQ  = (const float*)d_in[3];
  const float* WK  = (const float*)d_in[4];
  const float* WV  = (const float*)d_in[5];
  const float* WO  = (const float*)d_in[6];
  const float* l1s = (const float*)d_in[7];
  const float* l1b = (const float*)d_in[8];
  const float* l2s = (const float*)d_in[9];
  const float* l2b = (const float*)d_in[10];
  const float* Wi  = (const float*)d_in[11];
  const float* bi  = (const float*)d_in[12];
  const float* Wo2 = (const float*)d_in[13];
  const float* bo  = (const float*)d_in[14];
  float* out = (float*)d_out;

  const int  N = in_sizes[0] / 128;
  const long E = (long)in_sizes[1] / 128;

  char* ws = (char*)d_ws;
  size_t off = 0;
  auto alloc = [&](size_t b){ size_t o = off; off += (b + 255) & ~(size_t)255; return o; };
  const size_t WB = 128*128*sizeof(unsigned short);
  size_t oWQT = alloc(WB), oWKtT = alloc(WB), oWKbT = alloc(WB);
  size_t oWVtT = alloc(WB), oWVbT = alloc(WB), oWOT = alloc(WB);
  size_t oWinT = alloc(WB), oWouT = alloc(WB);
  size_t oQ   = alloc((size_t)N*128*2);
  size_t oYK  = alloc((size_t)N*128*2);
  size_t oYV  = alloc((size_t)N*128*2);
  size_t oEX  = alloc((size_t)E*4*4);
  size_t oDEN = alloc((size_t)N*4*4);
  size_t oAGG = alloc((size_t)N*128*4);
  size_t zero_bytes = (oAGG + (size_t)N*128*4) - oDEN;

  unsigned short* WQT  = (unsigned short*)(ws + oWQT);
  unsigned short* WKtT = (unsigned short*)(ws + oWKtT);
  unsigned short* WKbT = (unsigned short*)(ws + oWKbT);
  unsigned short* WVtT = (unsigned short*)(ws + oWVtT);
  unsigned short* WVbT = (unsigned short*)(ws + oWVbT);
  unsigned short* WOT  = (unsigned short*)(ws + oWOT);
  unsigned short* WinT = (unsigned short*)(ws + oWinT);
  unsigned short* WouT = (unsigned short*)(ws + oWouT);
  unsigned short* Qbf  = (unsigned short*)(ws + oQ);
  unsigned short* YKbf = (unsigned short*)(ws + oYK);
  unsigned short* YVbf = (unsigned short*)(ws + oYV);
  float* exw = (float*)(ws + oEX);
  float* den = (float*)(ws + oDEN);
  float* agg = (float*)(ws + oAGG);
  float* H1g = out;   // H1 lives in d_out; k_ffn reads+rewrites it in place

  const int nbN = (N + 127) / 128;
  const int nbE = (int)((E + 127) / 128);

  k_zero<<<2048, 256, 0, stream>>>((float4*)(ws + oDEN), (long)(zero_bytes / 16));
  k_wprep<<<64, 256, 0, stream>>>(WQ, WK, WV, WO, Wi, Wo2,
                                  WQT, WKtT, WKbT, WVtT, WVbT, WOT, WinT, WouT);
  k_nodeprep<<<nbN, 256, 0, stream>>>(hV, l1s, l1b, WQT, WKbT, WVbT, Qbf, YKbf, YVbf, N);
  k_edge1<<<nbE, 256, 0, stream>>>(hE, ei, WKtT, Qbf, YKbf, exw, den, E, N);
  k_edge2<<<nbE, 256, 0, stream>>>(hE, ei, WVtT, YVbf, exw, den, agg, E, N);
  k_attnout<<<nbN, 256, 0, stream>>>(hV, agg, WOT, H1g, N);
  k_ffn<<<nbN, 256, 0, stream>>>(H1g, l2s, l2b, WinT, WouT, bi, bo, out, N);
}

// Round 3
// 769.705 us; speedup vs baseline: 7.4884x; 7.4884x over previous
//
#include <hip/hip_runtime.h>

// Graph-transformer layer, MI355X. N nodes, E edges, H=128, 4 heads x d=32.
// R3: destination-sorted edges (counting sort), fused single edge pass
// (K-logits-exp-V-aggregate), unnormalized num/den aggregation with LDS
// segment-reduce -> plain stores for fully-owned rows, atomics only at run
// boundaries. Kills the 3.2GB atomic write traffic that was 93% of runtime.

typedef __bf16 bf16x8 __attribute__((ext_vector_type(8)));
typedef float f32x4 __attribute__((ext_vector_type(4)));
typedef unsigned short u16x8 __attribute__((ext_vector_type(8)));

#define DEV static __device__ __forceinline__

DEV unsigned short f2b(float f){
  union { float f; unsigned u; } v; v.f = f;
  unsigned r = (v.u + 0x7FFFu + ((v.u >> 16) & 1u)) >> 16;   // RNE
  return (unsigned short)r;
}
DEV float b2f(unsigned short h){
  union { unsigned u; float f; } v; v.u = ((unsigned)h) << 16; return v.f;
}
DEV f32x4 mfma16(bf16x8 a, bf16x8 b, f32x4 c){
  return __builtin_amdgcn_mfma_f32_16x16x32_bf16(a, b, c, 0, 0, 0);
}
DEV u16x8 pack8(float4 a, float4 b){
  u16x8 p;
  p[0]=f2b(a.x); p[1]=f2b(a.y); p[2]=f2b(a.z); p[3]=f2b(a.w);
  p[4]=f2b(b.x); p[5]=f2b(b.y); p[6]=f2b(b.z); p[7]=f2b(b.w);
  return p;
}
DEV float sspf(float x){  // shifted softplus
  return fmaxf(x, 0.f) + log1pf(expf(-fabsf(x))) - 0.69314718055994531f;
}
// edge_index layout probe: int32 normally; if raw int64 words, odd words == 0.
DEV int idx64probe(const int* __restrict__ ei){
  return (ei[1] | ei[3] | ei[5] | ei[7] | ei[9]) == 0;
}
DEV int ld_row(const int* __restrict__ ei, long eg, long E, int is64, int N){
  int v = is64 ? ei[2*eg] : ei[eg];
  return min(max(v, 0), N - 1);
}
DEV int ld_col(const int* __restrict__ ei, long eg, long E, int is64, int N){
  int v = is64 ? ei[2*(E + eg)] : ei[E + eg];
  return min(max(v, 0), N - 1);
}
DEV unsigned swz(unsigned byteoff, unsigned row){
  return byteoff ^ ((row & 7u) << 4);
}

// 128x128 (M x N) = A(128x128 bf16, LDS, XOR-swizzled) @ WT(bf16, [n][k]).
// 4 waves, each a 64x64 tile via 4x4 16x16x32 MFMAs.
DEV void mma128(const unsigned short* At, const unsigned short* __restrict__ WT,
                int t, f32x4 (&acc)[4][4]){
  const int l = t & 63;
  const int wm = (t >> 7) & 1, wn = (t >> 6) & 1;
#pragma unroll
  for (int m = 0; m < 4; ++m)
#pragma unroll
    for (int n = 0; n < 4; ++n)
      acc[m][n] = f32x4{0.f, 0.f, 0.f, 0.f};
#pragma unroll
  for (int kk = 0; kk < 4; ++kk){
    bf16x8 a[4], b[4];
#pragma unroll
    for (int m = 0; m < 4; ++m){
      int row = wm*64 + m*16 + (l & 15);
      a[m] = *(const bf16x8*)((const char*)At +
              swz((unsigned)(row*256 + kk*64 + ((l >> 4) & 3)*16), (unsigned)row));
    }
#pragma unroll
    for (int n = 0; n < 4; ++n){
      int col = wn*64 + n*16 + (l & 15);
      b[n] = *(const bf16x8*)(WT + col*128 + kk*32 + ((l >> 4) & 3)*8);
    }
#pragma unroll
    for (int m = 0; m < 4; ++m)
#pragma unroll
      for (int n = 0; n < 4; ++n)
        acc[m][n] = mfma16(a[m], b[n], acc[m][n]);
  }
}
// store MFMA acc as bf16 into swizzled LDS tile (plain store)
DEV void store_acc(unsigned short* Tt, const f32x4 (&acc)[4][4], int t){
  const int l = t & 63, wm = (t >> 7) & 1, wn = (t >> 6) & 1;
#pragma unroll
  for (int m = 0; m < 4; ++m)
#pragma unroll
    for (int reg = 0; reg < 4; ++reg){
      int er = wm*64 + m*16 + ((l >> 4) & 3)*4 + reg;
#pragma unroll
      for (int n = 0; n < 4; ++n){
        int col = wn*64 + n*16 + (l & 15);
        *(unsigned short*)((char*)Tt + swz((unsigned)(er*256 + col*2), (unsigned)er))
            = f2b(acc[m][n][reg]);
      }
    }
}

__global__ void k_zero(float4* __restrict__ p, long n){
  long i = (long)blockIdx.x * blockDim.x + threadIdx.x;
  const long st = (long)gridDim.x * blockDim.x;
  const float4 z = {0.f, 0.f, 0.f, 0.f};
  for (; i < n; i += st) p[i] = z;
}

// ---- weight prep: fp32 [k][n] -> bf16 [n][k] blobs ----
__global__ void k_wprep(const float* __restrict__ WQ, const float* __restrict__ WK,
                        const float* __restrict__ WV, const float* __restrict__ WO,
                        const float* __restrict__ Wi, const float* __restrict__ Wo2,
                        unsigned short* WQT, unsigned short* WKtT, unsigned short* WKbT,
                        unsigned short* WVtT, unsigned short* WVbT, unsigned short* WOT,
                        unsigned short* WinT, unsigned short* WouT){
  int id = blockIdx.x * 256 + threadIdx.x;
  int n = id >> 7, k = id & 127;
  int d = n * 128 + k;
  WQT[d]  = f2b(WQ[k*128 + n]);
  WKtT[d] = f2b(WK[k*128 + n]);
  WKbT[d] = f2b(WK[(k+128)*128 + n]);
  WVtT[d] = f2b(WV[k*128 + n]);
  WVbT[d] = f2b(WV[(k+128)*128 + n]);
  WOT[d]  = f2b(WO[k*128 + n]);
  WinT[d] = f2b(Wi[k*128 + n]);
  WouT[d] = f2b(Wo2[k*128 + n]);
}

// ---- counting sort by destination row ----
__global__ void k_hist(const int* __restrict__ ei, int* __restrict__ cnt, long E, int N){
  const int is64 = idx64probe(ei);
  long i = (long)blockIdx.x * blockDim.x + threadIdx.x;
  const long st = (long)gridDim.x * blockDim.x;
  for (; i < E; i += st) atomicAdd(&cnt[ld_row(ei, i, E, is64, N)], 1);
}

DEV int wave_incl_scan(int v, int lane){
#pragma unroll
  for (int ofs = 1; ofs < 64; ofs <<= 1){
    int u = __shfl_up(v, ofs, 64);
    if (lane >= ofs) v += u;
  }
  return v;
}

__global__ __launch_bounds__(1024) void k_scan(const int* __restrict__ cnt,
                                               int* __restrict__ rowStart,
                                               int* __restrict__ cursor, int N){
  __shared__ int wsum[16], woff[16];
  __shared__ int carry;
  const int t = threadIdx.x, lane = t & 63, w = t >> 6;
  if (t == 0) carry = 0;
  for (int base = 0; base < N; base += 1024){
    __syncthreads();
    int v = (base + t < N) ? cnt[base + t] : 0;
    int incl = wave_incl_scan(v, lane);
    if (lane == 63) wsum[w] = incl;
    __syncthreads();
    if (t == 0){
      int run = carry;
#pragma unroll
      for (int i = 0; i < 16; ++i){ woff[i] = run; run += wsum[i]; }
      carry = run;
    }
    __syncthreads();
    int excl = woff[w] + incl - v;
    if (base + t < N){ rowStart[base + t] = excl; cursor[base + t] = excl; }
  }
  __syncthreads();
  if (t == 0) rowStart[N] = carry;
}

__global__ void k_scatter(const int* __restrict__ ei, int* __restrict__ cursor,
                          int* __restrict__ perm, int* __restrict__ rowsS,
                          int* __restrict__ colS, long E, int N){
  const int is64 = idx64probe(ei);
  long i = (long)blockIdx.x * blockDim.x + threadIdx.x;
  const long st = (long)gridDim.x * blockDim.x;
  for (; i < E; i += st){
    int r = ld_row(ei, i, E, is64, N);
    int pos = atomicAdd(&cursor[r], 1);
    perm[pos] = (int)i;
    rowsS[pos] = r;
    colS[pos] = ld_col(ei, i, E, is64, N);
  }
}

// ---- node prep: LN1(h_V) -> y ; Q=y@WQ, YK=y@WKbot, YV=y@WVbot (bf16) ----
__global__ __launch_bounds__(256) void k_nodeprep(
    const float* __restrict__ hV, const float* __restrict__ l1s, const float* __restrict__ l1b,
    const unsigned short* __restrict__ WQT, const unsigned short* __restrict__ WKbT,
    const unsigned short* __restrict__ WVbT,
    unsigned short* __restrict__ Qbf, unsigned short* __restrict__ YKbf,
    unsigned short* __restrict__ YVbf, int N){
  __shared__ unsigned short At[128*128];
  __shared__ float ps[256], pss[256];
  __shared__ float scs[128], bis[128];
  const int t = threadIdx.x;
  if (t < 128){ scs[t] = l1s[t]; bis[t] = l1b[t]; }
  const int r0 = blockIdx.x * 128;
  const int rl = t & 127, hf = t >> 7;
  const int r = r0 + rl;
  const float4* xp = (const float4*)(hV + (size_t)r*128 + hf*64);
  float s = 0.f, ss = 0.f;
  if (r < N){
#pragma unroll
    for (int i = 0; i < 16; ++i){
      float4 v = xp[i];
      s  += (v.x + v.y) + (v.z + v.w);
      ss += (v.x*v.x + v.y*v.y) + (v.z*v.z + v.w*v.w);
    }
  }
  ps[t] = s; pss[t] = ss;
  __syncthreads();
  const float mu  = (ps[t] + ps[t ^ 128]) * 0.0078125f;
  const float var = (pss[t] + pss[t ^ 128]) * 0.0078125f - mu*mu;
  const float rs  = rsqrtf(var + 1e-5f);
#pragma unroll
  for (int i = 0; i < 8; ++i){
    const int c = hf*64 + i*8;
    u16x8 p = {0,0,0,0,0,0,0,0};
    if (r < N){
      float4 v0 = xp[2*i], v1 = xp[2*i+1];
      p[0] = f2b((v0.x - mu)*rs*scs[c+0] + bis[c+0]);
      p[1] = f2b((v0.y - mu)*rs*scs[c+1] + bis[c+1]);
      p[2] = f2b((v0.z - mu)*rs*scs[c+2] + bis[c+2]);
      p[3] = f2b((v0.w - mu)*rs*scs[c+3] + bis[c+3]);
      p[4] = f2b((v1.x - mu)*rs*scs[c+4] + bis[c+4]);
      p[5] = f2b((v1.y - mu)*rs*scs[c+5] + bis[c+5]);
      p[6] = f2b((v1.z - mu)*rs*scs[c+6] + bis[c+6]);
      p[7] = f2b((v1.w - mu)*rs*scs[c+7] + bis[c+7]);
    }
    *(u16x8*)((char*)At + swz((unsigned)(rl*256 + c*2), (unsigned)rl)) = p;
  }
  __syncthreads();
  const int l = t & 63, wm = (t >> 7) & 1, wn = (t >> 6) & 1;
  f32x4 acc[4][4];
  for (int g = 0; g < 3; ++g){
    const unsigned short* WT = (g == 0) ? WQT : (g == 1) ? WKbT : WVbT;
    unsigned short* O = (g == 0) ? Qbf : (g == 1) ? YKbf : YVbf;
    mma128(At, WT, t, acc);
#pragma unroll
    for (int m = 0; m < 4; ++m)
#pragma unroll
      for (int reg = 0; reg < 4; ++reg){
        int row = wm*64 + m*16 + ((l >> 4) & 3)*4 + reg;
        int gr = r0 + row;
        if (gr < N){
#pragma unroll
          for (int n = 0; n < 4; ++n){
            int col = wn*64 + n*16 + (l & 15);
            O[(size_t)gr*128 + col] = f2b(acc[m][n][reg]);
          }
        }
      }
  }
}

// ---- fused edge pass (sorted order): K-top MFMA, logits+exp, V-top MFMA,
//      LDS segment-reduce of {exp*V, exp} -> num/den (plain store or atomic) ----
__global__ __launch_bounds__(256, 2) void k_edge(
    const float* __restrict__ hE,
    const unsigned short* __restrict__ WKtT, const unsigned short* __restrict__ WVtT,
    const unsigned short* __restrict__ Qbf, const unsigned short* __restrict__ YKbf,
    const unsigned short* __restrict__ YVbf,
    const int* __restrict__ perm, const int* __restrict__ rowsS,
    const int* __restrict__ colS, const int* __restrict__ rowStart,
    float* __restrict__ num, float* __restrict__ den, long E){
  __shared__ unsigned short At[128*128];   // h_E tile (bf16, swizzled)
  __shared__ unsigned short Kt[128*128];   // K tile, then V tile
  __shared__ float aS[128][4];             // exp(logit) per edge/head
  __shared__ int permT[128], rowsT[128], colT[128];
  const int t = threadIdx.x;
  const long e0 = (long)blockIdx.x * 128;
  if (t < 128){
    long p = e0 + t;
    int pe = (p < E) ? perm[p] : -1;
    permT[t] = pe;
    rowsT[t] = (p < E) ? rowsS[p] : -1;
    colT[t]  = (p < E) ? colS[p] : 0;
  }
  __syncthreads();
  // stage h_E rows (gather by perm) -> At
#pragma unroll
  for (int i = 0; i < 8; ++i){
    int cc = t + i*256;
    int row = cc >> 4, ck = (cc & 15)*8;
    int pe = permT[row];
    u16x8 pkd = {0,0,0,0,0,0,0,0};
    if (pe >= 0){
      const float4* src = (const float4*)(hE + (size_t)pe*128 + ck);
      pkd = pack8(src[0], src[1]);
    }
    *(u16x8*)((char*)At + swz((unsigned)(row*256 + ck*2), (unsigned)row)) = pkd;
  }
  __syncthreads();
  f32x4 acc[4][4];
  mma128(At, WKtT, t, acc);      // K_top = h_E @ WKtop
  store_acc(Kt, acc, t);
  __syncthreads();
  {  // logits = Q[row] . (K_top + YK[col]) per head; exp
    const int e = t >> 1, hf = t & 1;
    const int r = rowsT[e];
    const u16x8* qp  = (const u16x8*)(Qbf  + (size_t)(r < 0 ? 0 : r)*128 + hf*64);
    const u16x8* ykp = (const u16x8*)(YKbf + (size_t)colT[e]*128 + hf*64);
    float lg0 = 0.f, lg1 = 0.f;
#pragma unroll
    for (int i = 0; i < 8; ++i){
      u16x8 q = qp[i], yk = ykp[i];
      u16x8 k = *(const u16x8*)((const char*)Kt +
          swz((unsigned)(e*256 + hf*128 + i*16), (unsigned)e));
      float d = 0.f;
#pragma unroll
      for (int j = 0; j < 8; ++j) d += b2f(q[j]) * (b2f(k[j]) + b2f(yk[j]));
      if (i < 4) lg0 += d; else lg1 += d;
    }
    aS[e][2*hf]     = (r >= 0) ? expf(lg0) : 0.f;
    aS[e][2*hf + 1] = (r >= 0) ? expf(lg1) : 0.f;
  }
  __syncthreads();               // all reads of Kt done
  mma128(At, WVtT, t, acc);      // V_top = h_E @ WVtop
  store_acc(Kt, acc, t);
  __syncthreads();
  {  // V += YV[col] (vectorized LDS RMW in edge layout)
    const int e = t >> 1, hf = t & 1;
    const u16x8* src = (const u16x8*)(YVbf + (size_t)colT[e]*128 + hf*64);
#pragma unroll
    for (int i = 0; i < 8; ++i){
      u16x8* p = (u16x8*)((char*)Kt + swz((unsigned)(e*256 + hf*128 + i*16), (unsigned)e));
      u16x8 a = *p, b = src[i], o;
#pragma unroll
      for (int j = 0; j < 8; ++j) o[j] = f2b(b2f(a[j]) + b2f(b[j]));
      *p = o;
    }
  }
  __syncthreads();
  {  // segment reduce: runs of equal row; plain store iff run == full segment
    const int c = t & 127, half = t >> 7, hh = c >> 5;
    const bool doDen = (c < 4);
    const int eb = half * 64;
    float accv = 0.f, accd = 0.f;
    int cur = rowsT[eb];
    long rs = e0 + eb;
    for (int e = eb; e < eb + 64; ++e){
      int r = rowsT[e];
      if (r != cur){
        if (cur >= 0){
          long re = e0 + e;
          bool own = (rowStart[cur] == (int)rs) && (rowStart[cur+1] == (int)re);
          float* np = num + (size_t)cur*128 + c;
          if (own) *np = accv; else atomicAdd(np, accv);
          if (doDen){
            float* dp = den + (size_t)cur*4 + c;
            if (own) *dp = accd; else atomicAdd(dp, accd);
          }
        }
        cur = r; rs = e0 + e; accv = 0.f; accd = 0.f;
      }
      float a = aS[e][hh];
      accv += a * b2f(*(const unsigned short*)((const char*)Kt +
                swz((unsigned)(e*256 + c*2), (unsigned)e)));
      if (doDen) accd += aS[e][c];
    }
    if (cur >= 0){
      long re = e0 + eb + 64;
      bool own = (rowStart[cur] == (int)rs) && (rowStart[cur+1] == (int)re);
      float* np = num + (size_t)cur*128 + c;
      if (own) *np = accv; else atomicAdd(np, accv);
      if (doDen){
        float* dp = den + (size_t)cur*4 + c;
        if (own) *dp = accd; else atomicAdd(dp, accd);
      }
    }
  }
}

// ---- attn out: h1 = h_V + ssp(num/den/sqrt(d)) @ W_O ----
__global__ __launch_bounds__(256) void k_attnout(
    const float* __restrict__ hV, const float* __restrict__ num,
    const float* __restrict__ den,
    const unsigned short* __restrict__ WOT, float* __restrict__ H1, int N){
  __shared__ unsigned short At[128*128];
  const int t = threadIdx.x;
  const int r0 = blockIdx.x * 128;
  const int rl = t & 127, hf = t >> 7;
  const int r = r0 + rl;
  const float4* ap = (const float4*)(num + (size_t)r*128 + hf*64);
  const float inv = 0.17677669529663687f;  // 1/sqrt(32)
  float i0 = 0.f, i1 = 0.f;
  if (r < N){
    float d0 = den[(size_t)r*4 + 2*hf], d1 = den[(size_t)r*4 + 2*hf + 1];
    i0 = (d0 > 0.f) ? inv / d0 : 0.f;
    i1 = (d1 > 0.f) ? inv / d1 : 0.f;
  }
#pragma unroll
  for (int i = 0; i < 8; ++i){
    u16x8 p = {0,0,0,0,0,0,0,0};
    if (r < N){
      float sc = (i < 4) ? i0 : i1;
      float4 v0 = ap[2*i], v1 = ap[2*i+1];
      p[0]=f2b(sspf(v0.x*sc)); p[1]=f2b(sspf(v0.y*sc)); p[2]=f2b(sspf(v0.z*sc)); p[3]=f2b(sspf(v0.w*sc));
      p[4]=f2b(sspf(v1.x*sc)); p[5]=f2b(sspf(v1.y*sc)); p[6]=f2b(sspf(v1.z*sc)); p[7]=f2b(sspf(v1.w*sc));
    }
    *(u16x8*)((char*)At + swz((unsigned)(rl*256 + hf*128 + i*16), (unsigned)rl)) = p;
  }
  __syncthreads();
  f32x4 acc[4][4];
  mma128(At, WOT, t, acc);
  const int l = t & 63, wm = (t >> 7) & 1, wn = (t >> 6) & 1;
#pragma unroll
  for (int m = 0; m < 4; ++m)
#pragma unroll
    for (int reg = 0; reg < 4; ++reg){
      int row = wm*64 + m*16 + ((l >> 4) & 3)*4 + reg;
      int gr = r0 + row;
      if (gr < N){
#pragma unroll
        for (int n = 0; n < 4; ++n){
          int col = wn*64 + n*16 + (l & 15);
          H1[(size_t)gr*128 + col] = acc[m][n][reg] + hV[(size_t)gr*128 + col];
        }
      }
    }
}

// ---- FFN: out = h1 + (relu(LN2(h1)@Win + bin)@Wout + bout), out==H1 ok ----
__global__ __launch_bounds__(256) void k_ffn(
    const float* __restrict__ H1, const float* __restrict__ l2s, const float* __restrict__ l2b,
    const unsigned short* __restrict__ WinT, const unsigned short* __restrict__ WouT,
    const float* __restrict__ bin, const float* __restrict__ bou,
    float* __restrict__ out, int N){
  __shared__ unsigned short At[128*128];
  __shared__ float ps[256], pss[256];
  __shared__ float scs[128], bis[128];
  const int t = threadIdx.x;
  if (t < 128){ scs[t] = l2s[t]; bis[t] = l2b[t]; }
  const int r0 = blockIdx.x * 128;
  const int rl = t & 127, hf = t >> 7;
  const int r = r0 + rl;
  const float4* xp = (const float4*)(H1 + (size_t)r*128 + hf*64);
  float s = 0.f, ss = 0.f;
  float4 xv[16];
  if (r < N){
#pragma unroll
    for (int i = 0; i < 16; ++i){
      float4 v = xp[i];
      xv[i] = v;
      s  += (v.x + v.y) + (v.z + v.w);
      ss += (v.x*v.x + v.y*v.y) + (v.z*v.z + v.w*v.w);
    }
  }
  ps[t] = s; pss[t] = ss;
  __syncthreads();
  const float mu  = (ps[t] + ps[t ^ 128]) * 0.0078125f;
  const float var = (pss[t] + pss[t ^ 128]) * 0.0078125f - mu*mu;
  const float rs  = rsqrtf(var + 1e-5f);
#pragma unroll
  for (int i = 0; i < 8; ++i){
    const int c = hf*64 + i*8;
    u16x8 p = {0,0,0,0,0,0,0,0};
    if (r < N){
      float4 v0 = xv[2*i], v1 = xv[2*i+1];
      p[0] = f2b((v0.x - mu)*rs*scs[c+0] + bis[c+0]);
      p[1] = f2b((v0.y - mu)*rs*scs[c+1] + bis[c+1]);
      p[2] = f2b((v0.z - mu)*rs*scs[c+2] + bis[c+2]);
      p[3] = f2b((v0.w - mu)*rs*scs[c+3] + bis[c+3]);
      p[4] = f2b((v1.x - mu)*rs*scs[c+4] + bis[c+4]);
      p[5] = f2b((v1.y - mu)*rs*scs[c+5] + bis[c+5]);
      p[6] = f2b((v1.z - mu)*rs*scs[c+6] + bis[c+6]);
      p[7] = f2b((v1.w - mu)*rs*scs[c+7] + bis[c+7]);
    }
    *(u16x8*)((char*)At + swz((unsigned)(rl*256 + c*2), (unsigned)rl)) = p;
  }
  __syncthreads();
  f32x4 acc[4][4];
  mma128(At, WinT, t, acc);
  const int l = t & 63, wm = (t >> 7) & 1, wn = (t >> 6) & 1;
  unsigned short hv[4][4][4];
#pragma unroll
  for (int m = 0; m < 4; ++m)
#pragma unroll
    for (int n = 0; n < 4; ++n)
#pragma unroll
      for (int reg = 0; reg < 4; ++reg){
        int col = wn*64 + n*16 + (l & 15);
        float v = acc[m][n][reg] + bin[col];
        hv[m][n][reg] = f2b(fmaxf(v, 0.f));
      }
  __syncthreads();
#pragma unroll
  for (int m = 0; m < 4; ++m)
#pragma unroll
    for (int reg = 0; reg < 4; ++reg){
      int row = wm*64 + m*16 + ((l >> 4) & 3)*4 + reg;
#pragma unroll
      for (int n = 0; n < 4; ++n){
        int col = wn*64 + n*16 + (l & 15);
        *(unsigned short*)((char*)At + swz((unsigned)(row*256 + col*2), (unsigned)row))
            = hv[m][n][reg];
      }
    }
  __syncthreads();
  mma128(At, WouT, t, acc);
#pragma unroll
  for (int m = 0; m < 4; ++m)
#pragma unroll
    for (int reg = 0; reg < 4; ++reg){
      int row = wm*64 + m*16 + ((l >> 4) & 3)*4 + reg;
      int gr = r0 + row;
      if (gr < N){
#pragma unroll
        for (int n = 0; n < 4; ++n){
          int col = wn*64 + n*16 + (l & 15);
          out[(size_t)gr*128 + col] = acc[m][n][reg] + bou[col] + H1[(size_t)gr*128 + col];
        }
      }
    }
}

extern "C" void kernel_launch(void* const* d_in, const int* in_sizes, int n_in,
                              void* d_out, int out_size, void* d_ws, size_t ws_size,
                              hipStream_t stream)
{
  const float* hV  = (const float*)d_in[0];
  const float* hE  = (const float*)d_in[1];
  const int*   ei  = (const int*)d_in[2];
  const float* WQ  = (const float*)d_in[3];
  const float* WK  = (const float*)d_in[4];
  const float* WV  = (const float*)d_in[5];
  const float* WO  = (const float*)d_in[6];
  const float* l1s = (const float*)d_in[7];
  const float* l1b = (const float*)d_in[8];
  const float* l2s = (const float*)d_in[9];
  const float* l2b = (const float*)d_in[10];
  const float* Wi  = (const float*)d_in[11];
  const float* bi  = (const float*)d_in[12];
  const float* Wo2 = (const float*)d_in[13];
  const float* bo  = (const float*)d_in[14];
  float* out = (float*)d_out;

  const int  N = in_sizes[0] / 128;
  const long E = (long)in_sizes[1] / 128;

  char* ws = (char*)d_ws;
  size_t off = 0;
  auto alloc = [&](size_t b){ size_t o = off; off += (b + 255) & ~(size_t)255; return o; };
  const size_t WB = 128*128*sizeof(unsigned short);
  size_t oWQT = alloc(WB), oWKtT = alloc(WB), oWKbT = alloc(WB);
  size_t oWVtT = alloc(WB), oWVbT = alloc(WB), oWOT = alloc(WB);
  size_t oWinT = alloc(WB), oWouT = alloc(WB);
  size_t oQ    = alloc((size_t)N*128*2);
  size_t oYK   = alloc((size_t)N*128*2);
  size_t oYV   = alloc((size_t)N*128*2);
  size_t oPERM = alloc((size_t)E*4);
  size_t oROWS = alloc((size_t)E*4);
  size_t oCOLS = alloc((size_t)E*4);
  size_t oRST  = alloc((size_t)(N+1)*4);
  size_t oCUR  = alloc((size_t)N*4);
  size_t oCNT  = alloc((size_t)N*4);        // zeroed region starts here
  size_t oDEN  = alloc((size_t)N*4*4);
  size_t oNUM  = alloc((size_t)N*128*4);
  size_t zero_bytes = (oNUM + (size_t)N*128*4) - oCNT;

  unsigned short* WQT  = (unsigned short*)(ws + oWQT);
  unsigned short* WKtT = (unsigned short*)(ws + oWKtT);
  unsigned short* WKbT = (unsigned short*)(ws + oWKbT);
  unsigned short* WVtT = (unsigned short*)(ws + oWVtT);
  unsigned short* WVbT = (unsigned short*)(ws + oWVbT);
  unsigned short* WOT  = (unsigned short*)(ws + oWOT);
  unsigned short* WinT = (unsigned short*)(ws + oWinT);
  unsigned short* WouT = (unsigned short*)(ws + oWouT);
  unsigned short* Qbf  = (unsigned short*)(ws + oQ);
  unsigned short* YKbf = (unsigned short*)(ws + oYK);
  unsigned short* YVbf = (unsigned short*)(ws + oYV);
  int* perm  = (int*)(ws + oPERM);
  int* rowsS = (int*)(ws + oROWS);
  int* colS  = (int*)(ws + oCOLS);
  int* rowSt = (int*)(ws + oRST);
  int* cursor= (int*)(ws + oCUR);
  int* cnt   = (int*)(ws + oCNT);
  float* den = (float*)(ws + oDEN);
  float* num = (float*)(ws + oNUM);
  float* H1g = out;   // H1 lives in d_out; k_ffn rewrites in place

  const int nbN = (N + 127) / 128;
  const int nbE = (int)((E + 127) / 128);
  const int nbe = (int)((E + 255) / 256);

  k_zero<<<2048, 256, 0, stream>>>((float4*)(ws + oCNT), (long)(zero_bytes / 16));
  k_wprep<<<64, 256, 0, stream>>>(WQ, WK, WV, WO, Wi, Wo2,
                                  WQT, WKtT, WKbT, WVtT, WVbT, WOT, WinT, WouT);
  k_nodeprep<<<nbN, 256, 0, stream>>>(hV, l1s, l1b, WQT, WKbT, WVbT, Qbf, YKbf, YVbf, N);
  k_hist<<<nbe, 256, 0, stream>>>(ei, cnt, E, N);
  k_scan<<<1, 1024, 0, stream>>>(cnt, rowSt, cursor, N);
  k_scatter<<<nbe, 256, 0, stream>>>(ei, cursor, perm, rowsS, colS, E, N);
  k_edge<<<nbE, 256, 0, stream>>>(hE, WKtT, WVtT, Qbf, YKbf, YVbf,
                                  perm, rowsS, colS, rowSt, num, den, E);
  k_attnout<<<nbN, 256, 0, stream>>>(hV, num, den, WOT, H1g, N);
  k_ffn<<<nbN, 256, 0, stream>>>(H1g, l2s, l2b, WinT, WouT, bi, bo, out, N);
}